// Round 6
// baseline (230.987 us; speedup 1.0000x reference)
//
#include <hip/hip_runtime.h>
#include <hip/hip_bf16.h>
#include <stdint.h>

// Problem constants
#define B_ 32
#define N_ 4096
#define M_ 256
#define L_ 128
#define H_ 4
#define BN_ (B_ * N_)          // 131072 flattened rows

typedef __bf16 bf16x8 __attribute__((ext_vector_type(8)));
typedef float  f32x4  __attribute__((ext_vector_type(4)));

__device__ __forceinline__ unsigned short f2bf(float f) {
    // round-to-nearest-even f32 -> bf16
    unsigned int u = __float_as_uint(f);
    u += 0x7fffu + ((u >> 16) & 1u);
    return (unsigned short)(u >> 16);
}
__device__ __forceinline__ unsigned int pack2(float lo, float hi) {
    return (unsigned int)f2bf(lo) | ((unsigned int)f2bf(hi) << 16);
}

// async global->LDS, 16B per lane. LDS dest is wave-uniform base (+lane*16 by HW).
__device__ __forceinline__ void gload16(const void* g, void* l) {
    __builtin_amdgcn_global_load_lds(
        (const __attribute__((address_space(1))) unsigned int*)g,
        (__attribute__((address_space(3))) unsigned int*)l, 16, 0, 0);
}

// ---------------------------------------------------------------------------
// prep: V,U (H,M,L) f32 -> vu images [(h*8 + s)*2 + mat][128 l][32 m] bf16,
// swizzled (byte ^= (l&6)<<3 within the 64B row). Transpose via padded LDS.
// ---------------------------------------------------------------------------
__global__ void prep_vu_img(const float* __restrict__ V, const float* __restrict__ U,
                            unsigned short* __restrict__ vu) {
    __shared__ float slab[64][129];     // [m][l], padded
    const int b   = blockIdx.x;         // 32 = h(4) * ks64(4) * mat(2)
    const int mat = b & 1, ks = (b >> 1) & 3, h = b >> 3;
    const float* src = (mat ? U : V) + ((size_t)h * M_ + ks * 64) * L_;
    const int tid = threadIdx.x;
#pragma unroll
    for (int rep = 0; rep < 32; ++rep) {
        int idx = rep * 256 + tid;      // 8192 = 64m x 128l
        slab[idx >> 7][idx & 127] = src[(size_t)(idx >> 7) * L_ + (idx & 127)];
    }
    __syncthreads();
#pragma unroll
    for (int rep = 0; rep < 4; ++rep) {
        int cidx = rep * 256 + tid;     // 1024 chunks of 16B (two 8KB images)
        int l  = cidx >> 3;             // 0..127
        int kk = (cidx & 7) * 8;        // 0..56
        uint4 o;
        o.x = pack2(slab[kk + 0][l], slab[kk + 1][l]);
        o.y = pack2(slab[kk + 2][l], slab[kk + 3][l]);
        o.z = pack2(slab[kk + 4][l], slab[kk + 5][l]);
        o.w = pack2(slab[kk + 6][l], slab[kk + 7][l]);
        int tl = kk >> 5, kl = kk & 31;
        char* dst = (char*)vu + (((size_t)(h * 8 + ks * 2 + tl)) * 2 + mat) * 8192;
        int byte = (l * 64 + kl * 2) ^ ((l & 6) << 3);
        *(uint4*)(dst + byte) = o;
    }
}

// ---------------------------------------------------------------------------
// gemm_fast4: x->regs (f32 direct + in-reg bf16 convert), V/U via 3-buffer
// counted-vmcnt gload16 pipeline, 64x64 wave tiles.
// logits[b,h,n] = sum_l tanh(xV)*sigmoid(xU)*w[h,l]
// Block = 128 rows x 128 l x {V,U}, one (tile,h); wave wv: rows (wv&1)*64,
// l-cols (wv>>1)*64. Per step: 8 ds_read_b128 (B only) + 32 MFMA; A-frags
// packed in-register from 8 dwordx4 f32 loads (each 64B line fully used).
// Issue order per step: [pack x(t)] [load x(t+1)] [stage B(t+2)], so the
// top-of-step s_waitcnt vmcnt(4) drains exactly B(t)+x(t), keeps B(t+1) and
// x(t+1) relatives in flight (T3+T4). Epilogue joins l-halves via LDS part[].
// ---------------------------------------------------------------------------
__global__ __launch_bounds__(256, 2)
void gemm_fast4(const float* __restrict__ x,
                const unsigned short* __restrict__ vu,
                const float* __restrict__ w,
                float* __restrict__ logits) {
    __shared__ __align__(16) unsigned short vs[3][4096];   // 3 x 8KB
    __shared__ __align__(16) unsigned short us[3][4096];
    __shared__ float part[2][128];

    const int orig    = blockIdx.x;                 // 4096, %8==0 -> bijective
    const int logical = (orig & 7) * 512 + (orig >> 3);
    const int tile    = logical >> 2;
    const int h       = logical & 3;

    const int tid  = threadIdx.x;
    const int lane = tid & 63;
    const int wv   = tid >> 6;
    const int g    = lane >> 4;     // k-group 0..3 (k = g*8 + j)
    const int c    = lane & 15;     // A-row / B-col within fragment
    const int r0   = (wv & 1) * 64; // wave row base
    const int l0   = (wv >> 1) * 64;// wave l base

    f32x4 accV[4][4], accU[4][4];
#pragma unroll
    for (int rf = 0; rf < 4; ++rf)
#pragma unroll
        for (int cf = 0; cf < 4; ++cf) {
            accV[rf][cf] = (f32x4){0.f, 0.f, 0.f, 0.f};
            accU[rf][cf] = (f32x4){0.f, 0.f, 0.f, 0.f};
        }

    const int soff = wv * 2048;     // wave's quarter of each 8KB image

    // per-lane global srcs for B (pre-swizzled images; step stride 16384B)
    const char* gvs = (const char*)vu + (size_t)h * 131072 + soff + lane * 16;

    // per-lane x row pointers (f32), one per row-fragment
    const float* xp0 = x + ((size_t)tile * 128 + r0 +  0 + c) * M_ + g * 8;
    const float* xp1 = xp0 + 16 * M_;
    const float* xp2 = xp0 + 32 * M_;
    const float* xp3 = xp0 + 48 * M_;

    // swizzled LDS byte offsets for B fragments
    int boff[4];
#pragma unroll
    for (int cf = 0; cf < 4; ++cf) {
        int l = l0 + cf * 16 + c;
        boff[cf] = (l * 64 + g * 16) ^ ((l & 6) << 3);
    }

    float4 xr[8];          // raw f32 for next step's A-frags (const-indexed)
    bf16x8 fa0, fa1, fa2, fa3;

#define LOADX(T) do {                                                     \
        xr[0] = *(const float4*)(xp0 + (T) * 32);                         \
        xr[1] = *(const float4*)(xp0 + (T) * 32 + 4);                     \
        xr[2] = *(const float4*)(xp1 + (T) * 32);                         \
        xr[3] = *(const float4*)(xp1 + (T) * 32 + 4);                     \
        xr[4] = *(const float4*)(xp2 + (T) * 32);                         \
        xr[5] = *(const float4*)(xp2 + (T) * 32 + 4);                     \
        xr[6] = *(const float4*)(xp3 + (T) * 32);                         \
        xr[7] = *(const float4*)(xp3 + (T) * 32 + 4);                     \
    } while (0)

#define PK(F, A, Bv) do {                                                 \
        F[0] = (__bf16)(A).x; F[1] = (__bf16)(A).y;                       \
        F[2] = (__bf16)(A).z; F[3] = (__bf16)(A).w;                       \
        F[4] = (__bf16)(Bv).x; F[5] = (__bf16)(Bv).y;                     \
        F[6] = (__bf16)(Bv).z; F[7] = (__bf16)(Bv).w;                     \
    } while (0)

#define PACK() do {                                                       \
        PK(fa0, xr[0], xr[1]); PK(fa1, xr[2], xr[3]);                     \
        PK(fa2, xr[4], xr[5]); PK(fa3, xr[6], xr[7]);                     \
    } while (0)

#define STAGEB(T, BI) do {                                                \
        const char* _gv = gvs + (T) * 16384;                              \
        const char* _gu = _gv + 8192;                                     \
        gload16(_gv,        (char*)vs[BI] + soff);                        \
        gload16(_gv + 1024, (char*)vs[BI] + soff + 1024);                 \
        gload16(_gu,        (char*)us[BI] + soff);                        \
        gload16(_gu + 1024, (char*)us[BI] + soff + 1024);                 \
    } while (0)

#define COMPUTE(BI) do {                                                  \
        const char* _vb = (const char*)vs[BI];                            \
        const char* _ub = (const char*)us[BI];                            \
        _Pragma("unroll")                                                 \
        for (int cf = 0; cf < 4; ++cf) {                                  \
            bf16x8 bv = *(const bf16x8*)(_vb + boff[cf]);                 \
            bf16x8 bu = *(const bf16x8*)(_ub + boff[cf]);                 \
            accV[0][cf] = __builtin_amdgcn_mfma_f32_16x16x32_bf16(fa0, bv, accV[0][cf], 0, 0, 0); \
            accV[1][cf] = __builtin_amdgcn_mfma_f32_16x16x32_bf16(fa1, bv, accV[1][cf], 0, 0, 0); \
            accV[2][cf] = __builtin_amdgcn_mfma_f32_16x16x32_bf16(fa2, bv, accV[2][cf], 0, 0, 0); \
            accV[3][cf] = __builtin_amdgcn_mfma_f32_16x16x32_bf16(fa3, bv, accV[3][cf], 0, 0, 0); \
            accU[0][cf] = __builtin_amdgcn_mfma_f32_16x16x32_bf16(fa0, bu, accU[0][cf], 0, 0, 0); \
            accU[1][cf] = __builtin_amdgcn_mfma_f32_16x16x32_bf16(fa1, bu, accU[1][cf], 0, 0, 0); \
            accU[2][cf] = __builtin_amdgcn_mfma_f32_16x16x32_bf16(fa2, bu, accU[2][cf], 0, 0, 0); \
            accU[3][cf] = __builtin_amdgcn_mfma_f32_16x16x32_bf16(fa3, bu, accU[3][cf], 0, 0, 0); \
        }                                                                 \
    } while (0)

#define SCHED __builtin_amdgcn_sched_barrier(0)

    // steady-state step: wait B(t)+x(t) done (leave B(t+1) in flight),
    // barrier, pack, issue x(t+1), issue B(t+2), compute.
#define STEPF(T, BC, BN2) do {                                            \
        asm volatile("s_waitcnt vmcnt(4)" ::: "memory");                  \
        __builtin_amdgcn_s_barrier(); SCHED;                              \
        PACK(); SCHED;                                                    \
        LOADX((T) + 1); SCHED;                                            \
        STAGEB((T) + 2, BN2); SCHED;                                      \
        COMPUTE(BC);                                                      \
    } while (0)

    // prologue: B(0), x(0), B(1)  (issue order matters for vmcnt math)
    STAGEB(0, 0);
    SCHED;
    LOADX(0);
    SCHED;
    STAGEB(1, 1);
    SCHED;

    STEPF(0, 0, 2);
    STEPF(1, 1, 0);
    STEPF(2, 2, 1);
    STEPF(3, 0, 2);
    STEPF(4, 1, 0);
    STEPF(5, 2, 1);
    // t = 6: no B(8); still prefetch x(7)
    {
        asm volatile("s_waitcnt vmcnt(4)" ::: "memory");
        __builtin_amdgcn_s_barrier(); SCHED;
        PACK(); SCHED;
        LOADX(7); SCHED;
        COMPUTE(0);
    }
    // t = 7: drain everything
    {
        asm volatile("s_waitcnt vmcnt(0)" ::: "memory");
        __builtin_amdgcn_s_barrier(); SCHED;
        PACK(); SCHED;
        COMPUTE(1);
    }

#undef STEPF
#undef COMPUTE
#undef STAGEB
#undef PACK
#undef PK
#undef LOADX

    // ---- epilogue: gated = tanh(V)*sigmoid(U), dot w over this wave's 64 l,
    //      16-lane shuffle reduce, join l-halves via LDS part[].
    const float* wrow = w + h * L_ + l0;
#pragma unroll
    for (int rf = 0; rf < 4; ++rf) {
        float plog[4] = {0.f, 0.f, 0.f, 0.f};
#pragma unroll
        for (int cf = 0; cf < 4; ++cf) {
            float wvv = wrow[cf * 16 + c];
#pragma unroll
            for (int i = 0; i < 4; ++i) {
                float vvv = accV[rf][cf][i];
                float uu  = accU[rf][cf][i];
                vvv = fminf(fmaxf(vvv, -20.f), 20.f);
                float A = __expf(2.f * vvv);                // tanh = (A-1)/(A+1)
                float E = __expf(fminf(-uu, 30.f));         // sigmoid = 1/(1+E)
                float gg = __fdividef(A - 1.f, (A + 1.f) * (1.f + E));
                plog[i] += gg * wvv;
            }
        }
#pragma unroll
        for (int i = 0; i < 4; ++i) {
            float v = plog[i];
            v += __shfl_xor(v, 1);
            v += __shfl_xor(v, 2);
            v += __shfl_xor(v, 4);
            v += __shfl_xor(v, 8);      // sum over the 16 col-lanes
            if (c == 0)
                part[wv >> 1][r0 + rf * 16 + g * 4 + i] = v;
        }
    }
    __syncthreads();
    if (tid < 128) {
        float v = part[0][tid] + part[1][tid];
        int rowflat = tile * 128 + tid;
        int b = rowflat >> 12;
        int n = rowflat & (N_ - 1);
        logits[((size_t)b * H_ + h) * N_ + n] = v;
    }
}

// ---------------------------------------------------------------------------
// SLOW PATH (round-1 fallback, used only if ws_size is too small)
// ---------------------------------------------------------------------------
__global__ void prep_vu_slow(const float* __restrict__ V, const float* __restrict__ U,
                             unsigned short* __restrict__ Vt, unsigned short* __restrict__ Ut) {
    int idx = blockIdx.x * 256 + threadIdx.x;
    int m = idx & (M_ - 1);
    int l = (idx >> 8) & (L_ - 1);
    int h = idx >> 15;
    Vt[idx] = f2bf(V[((size_t)h * M_ + m) * L_ + l]);
    Ut[idx] = f2bf(U[((size_t)h * M_ + m) * L_ + l]);
}

#define BM 128
#define BK 64

__global__ __launch_bounds__(256, 2)
void gemm_logits(const float* __restrict__ x,
                 const unsigned short* __restrict__ Vt,
                 const unsigned short* __restrict__ Ut,
                 const float* __restrict__ w,
                 float* __restrict__ logits) {
    __shared__ __align__(16) unsigned short xs[BM * BK];
    __shared__ __align__(16) unsigned short vs[L_ * BK];
    __shared__ __align__(16) unsigned short us[L_ * BK];
    __shared__ float wl[L_];

    const int h    = blockIdx.x >> 10;
    const int tile = blockIdx.x & 1023;
    const int row0 = tile * BM;
    const int tid  = threadIdx.x;
    const int lane = tid & 63;
    const int wave = tid >> 6;

    if (tid < L_) wl[tid] = w[h * L_ + tid];

    f32x4 accV[2][8], accU[2][8];
#pragma unroll
    for (int rf = 0; rf < 2; ++rf)
#pragma unroll
        for (int cf = 0; cf < 8; ++cf) {
            accV[rf][cf] = (f32x4){0.f, 0.f, 0.f, 0.f};
            accU[rf][cf] = (f32x4){0.f, 0.f, 0.f, 0.f};
        }

    const unsigned short* Vh = Vt + (size_t)h * L_ * M_;
    const unsigned short* Uh = Ut + (size_t)h * L_ * M_;
    const int g = lane >> 4;
    const int c = lane & 15;

    for (int ks = 0; ks < 4; ++ks) {
        const int k0 = ks * BK;
        __syncthreads();
#pragma unroll
        for (int p = 0; p < 4; ++p) {
            int row = p * 32 + (tid >> 3);
            int kk  = (tid & 7) * 8;
            const float* gx = x + (size_t)(row0 + row) * M_ + k0 + kk;
            float4 a = *(const float4*)gx;
            float4 b = *(const float4*)(gx + 4);
            uint4 o;
            o.x = pack2(a.x, a.y); o.y = pack2(a.z, a.w);
            o.z = pack2(b.x, b.y); o.w = pack2(b.z, b.w);
            int byte = (row * BK + kk) * 2;
            byte ^= (row & 7) << 4;
            *(uint4*)((char*)xs + byte) = o;
        }
#pragma unroll
        for (int p = 0; p < 4; ++p) {
            int l  = p * 32 + (tid >> 3);
            int kk = (tid & 7) * 8;
            uint4 v = *(const uint4*)(Vh + (size_t)l * M_ + k0 + kk);
            uint4 u = *(const uint4*)(Uh + (size_t)l * M_ + k0 + kk);
            int byte = (l * BK + kk) * 2;
            byte ^= (l & 7) << 4;
            *(uint4*)((char*)vs + byte) = v;
            *(uint4*)((char*)us + byte) = u;
        }
        __syncthreads();
#pragma unroll
        for (int ksub = 0; ksub < 2; ++ksub) {
            bf16x8 afr[2];
#pragma unroll
            for (int rf = 0; rf < 2; ++rf) {
                int row = wave * 32 + rf * 16 + c;
                int byte = (row * BK + ksub * 32 + g * 8) * 2;
                byte ^= (row & 7) << 4;
                afr[rf] = *(const bf16x8*)((const char*)xs + byte);
            }
#pragma unroll
            for (int cf = 0; cf < 8; ++cf) {
                int l = cf * 16 + c;
                int byte = (l * BK + ksub * 32 + g * 8) * 2;
                byte ^= (l & 7) << 4;
                bf16x8 bv = *(const bf16x8*)((const char*)vs + byte);
                bf16x8 bu = *(const bf16x8*)((const char*)us + byte);
#pragma unroll
                for (int rf = 0; rf < 2; ++rf) {
                    accV[rf][cf] = __builtin_amdgcn_mfma_f32_16x16x32_bf16(afr[rf], bv, accV[rf][cf], 0, 0, 0);
                    accU[rf][cf] = __builtin_amdgcn_mfma_f32_16x16x32_bf16(afr[rf], bu, accU[rf][cf], 0, 0, 0);
                }
            }
        }
    }
#pragma unroll
    for (int rf = 0; rf < 2; ++rf) {
        float plog[4] = {0.f, 0.f, 0.f, 0.f};
#pragma unroll
        for (int cf = 0; cf < 8; ++cf) {
            float wvv = wl[cf * 16 + c];
#pragma unroll
            for (int i = 0; i < 4; ++i) {
                float vv = accV[rf][cf][i];
                float uu = accU[rf][cf][i];
                vv = fminf(fmaxf(vv, -20.f), 20.f);
                float e2v = __expf(2.f * vv);
                float t = __fdividef(e2v - 1.f, e2v + 1.f);
                float s = __fdividef(1.f, 1.f + __expf(-uu));
                plog[i] += t * s * wvv;
            }
        }
#pragma unroll
        for (int i = 0; i < 4; ++i) {
            float v = plog[i];
            v += __shfl_xor(v, 1);
            v += __shfl_xor(v, 2);
            v += __shfl_xor(v, 4);
            v += __shfl_xor(v, 8);
            if (c == 0) {
                int rowflat = row0 + wave * 32 + rf * 16 + g * 4 + i;
                int b = rowflat >> 12;
                int n = rowflat & (N_ - 1);
                logits[((size_t)b * H_ + h) * N_ + n] = v;
            }
        }
    }
}

// ---------------------------------------------------------------------------
// softmax^2 (first normalization cancels): a = e^2/sum(e^2), e = m*exp(m*l).
// ---------------------------------------------------------------------------
__global__ __launch_bounds__(256)
void softmax_att(const float* __restrict__ logits, const float* __restrict__ masks,
                 float* __restrict__ att) {
    const int bh = blockIdx.x;
    const int b = bh >> 2, h = bh & 3;
    __shared__ float e2s[N_];
    __shared__ float red[4];
    const int tid = threadIdx.x;

    float sum = 0.f;
#pragma unroll
    for (int i = 0; i < N_ / 256; ++i) {
        int n = i * 256 + tid;
        float lg = logits[((size_t)b * H_ + h) * N_ + n];
        float mv = masks[(size_t)b * N_ + n];
        float e = mv * __expf(mv * lg);
        float e2 = e * e;
        e2s[n] = e2;
        sum += e2;
    }
#pragma unroll
    for (int off = 32; off >= 1; off >>= 1) sum += __shfl_xor(sum, off);
    if ((tid & 63) == 0) red[tid >> 6] = sum;
    __syncthreads();
    float S = red[0] + red[1] + red[2] + red[3];
    float inv = 1.f / S;
#pragma unroll
    for (int i = 0; i < N_ / 256; ++i) {
        int n = i * 256 + tid;
        att[((size_t)h * B_ + b) * N_ + n] = e2s[n] * inv;
    }
}

// ---------------------------------------------------------------------------
// emb: 2-stage deterministic reduction.
// ---------------------------------------------------------------------------
#define NCH 32
#define CHUNK (N_ / NCH)   // 128

__global__ __launch_bounds__(256)
void emb_partial(const float* __restrict__ x, const float* __restrict__ att,
                 float* __restrict__ part) {
    const int bc = blockIdx.x;
    const int b = bc >> 5, ch = bc & 31;
    __shared__ float as[H_][CHUNK];
    const int tid = threadIdx.x;

    for (int i = tid; i < H_ * CHUNK; i += 256) {
        int hh = i >> 7;
        int j  = i & (CHUNK - 1);
        as[hh][j] = att[((size_t)hh * B_ + b) * N_ + ch * CHUNK + j];
    }
    __syncthreads();

    float a0 = 0.f, a1 = 0.f, a2 = 0.f, a3 = 0.f;
    const float* xp = x + ((size_t)b * N_ + ch * CHUNK) * M_ + tid;
#pragma unroll 4
    for (int j = 0; j < CHUNK; ++j) {
        float xv = xp[(size_t)j * M_];
        a0 += as[0][j] * xv;
        a1 += as[1][j] * xv;
        a2 += as[2][j] * xv;
        a3 += as[3][j] * xv;
    }
    float* pp = part + (size_t)bc * H_ * M_ + tid;
    pp[0 * M_] = a0; pp[1 * M_] = a1; pp[2 * M_] = a2; pp[3 * M_] = a3;
}

__global__ __launch_bounds__(256)
void emb_reduce(const float* __restrict__ part, float* __restrict__ emb) {
    int idx = blockIdx.x * 256 + threadIdx.x;
    int b = idx >> 10;
    int r = idx & 1023;
    float s = 0.f;
#pragma unroll
    for (int ci = 0; ci < NCH; ++ci)
        s += part[((size_t)(b * NCH + ci)) * (H_ * M_) + r];
    emb[idx] = s;
}

// ---------------------------------------------------------------------------
extern "C" void kernel_launch(void* const* d_in, const int* in_sizes, int n_in,
                              void* d_out, int out_size, void* d_ws, size_t ws_size,
                              hipStream_t stream) {
    const float* x     = (const float*)d_in[0];
    const float* masks = (const float*)d_in[1];
    const float* V     = (const float*)d_in[2];
    const float* U     = (const float*)d_in[3];
    const float* w     = (const float*)d_in[4];

    float* att = (float*)d_out;                       // (H,B,N,1)
    float* emb = att + (size_t)H_ * B_ * N_;          // (B,H*M)

    char* ws = (char*)d_ws;
    const size_t VU_BYTES  = (size_t)64 * 8192;               // 524,288
    const size_t LG_BYTES  = (size_t)B_ * H_ * N_ * 4;        // 2,097,152
    const size_t PT_BYTES  = (size_t)B_ * NCH * H_ * M_ * 4;  // 4,194,304
    const size_t NEED_FAST = VU_BYTES + LG_BYTES + PT_BYTES;

    float* logits;
    float* partp;

    if (ws_size >= NEED_FAST) {
        unsigned short* vuimg = (unsigned short*)ws;
        logits = (float*)(ws + VU_BYTES);
        partp  = (float*)(ws + VU_BYTES + LG_BYTES);

        prep_vu_img<<<32,   256, 0, stream>>>(V, U, vuimg);
        gemm_fast4 <<<4096, 256, 0, stream>>>(x, vuimg, w, logits);
    } else {
        unsigned short* Vt = (unsigned short*)ws;
        unsigned short* Ut = (unsigned short*)(ws + 262144);
        logits = (float*)(ws + 524288);
        partp  = (float*)(ws + 524288 + LG_BYTES);

        prep_vu_slow<<<512, 256, 0, stream>>>(V, U, Vt, Ut);
        gemm_logits <<<4096, 256, 0, stream>>>(x, Vt, Ut, w, logits);
    }

    softmax_att<<<B_ * H_,              256, 0, stream>>>(logits, masks, att);
    emb_partial<<<B_ * NCH,             256, 0, stream>>>(x, att, partp);
    emb_reduce <<<(B_ * H_ * M_) / 256, 256, 0, stream>>>(partp, emb);
}

// Round 7
// 181.147 us; speedup vs baseline: 1.2751x; 1.2751x over previous
//
#include <hip/hip_runtime.h>
#include <hip/hip_bf16.h>
#include <stdint.h>

// Problem constants
#define B_ 32
#define N_ 4096
#define M_ 256
#define L_ 128
#define H_ 4
#define BN_ (B_ * N_)          // 131072 flattened rows

typedef __bf16 bf16x8 __attribute__((ext_vector_type(8)));
typedef float  f32x4  __attribute__((ext_vector_type(4)));

__device__ __forceinline__ unsigned short f2bf(float f) {
    // round-to-nearest-even f32 -> bf16
    unsigned int u = __float_as_uint(f);
    u += 0x7fffu + ((u >> 16) & 1u);
    return (unsigned short)(u >> 16);
}
__device__ __forceinline__ unsigned int pack2(float lo, float hi) {
    return (unsigned int)f2bf(lo) | ((unsigned int)f2bf(hi) << 16);
}

// async global->LDS, 16B per lane. LDS dest is wave-uniform base (+lane*16 by HW);
// global src is per-lane.
__device__ __forceinline__ void gload16(const void* g, void* l) {
    __builtin_amdgcn_global_load_lds(
        (const __attribute__((address_space(1))) unsigned int*)g,
        (__attribute__((address_space(3))) unsigned int*)l, 16, 0, 0);
}

// Image geometry: each K-step image is [128 rows][32 k] bf16 = 8192 B,
// row stride 64 B, swizzle byte ^= (row&6)<<3. 16-lane fragment groups read
// 16 distinct rows at fixed 16B col -> 2-way bank aliasing = free (G4, m136);
// measured 0 conflicts in rounds 4/5.

// ---------------------------------------------------------------------------
// prep 1: x (BN,256) f32 -> xb images: tile t in [0,1024), step s in [0,8):
// image base = (tile*8 + s)*8192.
// ---------------------------------------------------------------------------
__global__ void prep_x(const float* __restrict__ x, unsigned short* __restrict__ xb) {
    const int blk  = blockIdx.x;        // 4096 = 1024 tiles * 4 ks64
    const int tile = blk >> 2, ks = blk & 3;
    const int i    = threadIdx.x;
    const int kk   = (i & 7) * 8;       // 0..56 within the 64-col chunk
    const int tl   = kk >> 5;           // which 32-k image half
    const int kl   = kk & 31;
    char* dst = (char*)xb + ((size_t)tile * 8 + ks * 2 + tl) * 8192;
#pragma unroll
    for (int rep = 0; rep < 4; ++rep) {
        int row = rep * 32 + (i >> 3);
        const float* gx = x + (size_t)(tile * 128 + row) * M_ + ks * 64 + kk;
        float4 a = *(const float4*)gx;
        float4 b = *(const float4*)(gx + 4);
        uint4 o;
        o.x = pack2(a.x, a.y); o.y = pack2(a.z, a.w);
        o.z = pack2(b.x, b.y); o.w = pack2(b.z, b.w);
        int byte = (row * 64 + kl * 2) ^ ((row & 6) << 3);
        *(uint4*)(dst + byte) = o;
    }
}

// ---------------------------------------------------------------------------
// prep 2: V,U (H,M,L) f32 -> vu images [(h*8 + s)*2 + mat][128 l][32 m] bf16,
// swizzled. Transpose via padded LDS slab (conflict-free).
// ---------------------------------------------------------------------------
__global__ void prep_vu_img(const float* __restrict__ V, const float* __restrict__ U,
                            unsigned short* __restrict__ vu) {
    __shared__ float slab[64][129];     // [m][l], padded
    const int b   = blockIdx.x;         // 32 = h(4) * ks64(4) * mat(2)
    const int mat = b & 1, ks = (b >> 1) & 3, h = b >> 3;
    const float* src = (mat ? U : V) + ((size_t)h * M_ + ks * 64) * L_;
    const int tid = threadIdx.x;
#pragma unroll
    for (int rep = 0; rep < 32; ++rep) {
        int idx = rep * 256 + tid;      // 8192 = 64m x 128l
        slab[idx >> 7][idx & 127] = src[(size_t)(idx >> 7) * L_ + (idx & 127)];
    }
    __syncthreads();
#pragma unroll
    for (int rep = 0; rep < 4; ++rep) {
        int cidx = rep * 256 + tid;     // 1024 chunks of 16B (two 8KB images)
        int l  = cidx >> 3;             // 0..127
        int kk = (cidx & 7) * 8;        // 0..56
        uint4 o;
        o.x = pack2(slab[kk + 0][l], slab[kk + 1][l]);
        o.y = pack2(slab[kk + 2][l], slab[kk + 3][l]);
        o.z = pack2(slab[kk + 4][l], slab[kk + 5][l]);
        o.w = pack2(slab[kk + 6][l], slab[kk + 7][l]);
        int tl = kk >> 5, kl = kk & 31;
        char* dst = (char*)vu + (((size_t)(h * 8 + ks * 2 + tl)) * 2 + mat) * 8192;
        int byte = (l * 64 + kl * 2) ^ ((l & 6) << 3);
        *(uint4*)(dst + byte) = o;
    }
}

// ---------------------------------------------------------------------------
// gemm_fast5: round-5 pipeline, 2-buffer (48KB -> 3 blocks/CU) + T5 setprio.
// logits[b,h,n] = sum_l tanh(xV)*sigmoid(xU)*w[h,l]
// 16x16x32 MFMA; block = 128 rows x 128 l x {V,U}, one (tile,h); 4 waves.
// BK=32, 8 fully-unrolled K-steps, 1-deep prefetch:
//   step t: s_waitcnt vmcnt(0)  [stage(t)'s 6 loads, issued a full step ago,
//           ~1600cyc lookahead -> no stall]; s_barrier; issue stage(t+1);
//           setprio(1); 32 MFMA; setprio(0).
// Buffer recycle safety: a wave reaches the barrier only after its last MFMA
// issued, which required lgkmcnt-completion of all its ds_reads -> all reads
// of buf(t-1) are complete before any wave stages into it.
// ---------------------------------------------------------------------------
__global__ __launch_bounds__(256, 3)
void gemm_fast5(const unsigned short* __restrict__ xb,
                const unsigned short* __restrict__ vu,
                const float* __restrict__ w,
                float* __restrict__ logits) {
    __shared__ __align__(16) unsigned short xs[2][4096];   // 2 x 8KB
    __shared__ __align__(16) unsigned short vs[2][4096];
    __shared__ __align__(16) unsigned short us[2][4096];

    const int orig    = blockIdx.x;                 // 4096, %8==0 -> bijective
    const int logical = (orig & 7) * 512 + (orig >> 3);
    const int tile    = logical >> 2;
    const int h       = logical & 3;

    const int tid  = threadIdx.x;
    const int lane = tid & 63;
    const int wv   = tid >> 6;
    const int g    = lane >> 4;     // k-group 0..3 (k = g*8 + j)
    const int c    = lane & 15;     // row (A) / col (B) within fragment

    f32x4 accV[2][8], accU[2][8];
#pragma unroll
    for (int rf = 0; rf < 2; ++rf)
#pragma unroll
        for (int cf = 0; cf < 8; ++cf) {
            accV[rf][cf] = (f32x4){0.f, 0.f, 0.f, 0.f};
            accU[rf][cf] = (f32x4){0.f, 0.f, 0.f, 0.f};
        }

    const int soff = wv * 2048;     // this wave's quarter of each 8KB image

    // hoisted per-lane global sources (step strides: x 8192 B, v/u 16384 B)
    const char* gxs = (const char*)xb + (size_t)tile * 65536 + soff + lane * 16;
    const char* gvs = (const char*)vu + (size_t)h * 131072 + soff + lane * 16;
    const char* gus = gvs + 8192;

    // hoisted swizzled LDS read byte offsets (within an 8KB image)
    int ar = wv * 32 + c;
    const int aoff0 = (ar * 64 + g * 16) ^ ((ar & 6) << 3);
    const int aoff1 = ((ar + 16) * 64 + g * 16) ^ (((ar + 16) & 6) << 3);
    int boff[8];
#pragma unroll
    for (int cf = 0; cf < 8; ++cf) {
        int l = cf * 16 + c;
        boff[cf] = (l * 64 + g * 16) ^ ((l & 6) << 3);
    }

#define SCHED __builtin_amdgcn_sched_barrier(0)

#define STAGE(t, bufi) do {                                          \
        const char* _gx = gxs + (t) * 8192;                          \
        const char* _gv = gvs + (t) * 16384;                         \
        const char* _gu = gus + (t) * 16384;                         \
        gload16(_gx,        (char*)xs[bufi] + soff);                 \
        gload16(_gx + 1024, (char*)xs[bufi] + soff + 1024);          \
        gload16(_gv,        (char*)vs[bufi] + soff);                 \
        gload16(_gv + 1024, (char*)vs[bufi] + soff + 1024);          \
        gload16(_gu,        (char*)us[bufi] + soff);                 \
        gload16(_gu + 1024, (char*)us[bufi] + soff + 1024);          \
    } while (0)

    // prologue: stage step 0 into buf 0
    STAGE(0, 0);
    SCHED;

#pragma unroll
    for (int t = 0; t < 8; ++t) {
        // stage(t) was issued a full step ago (prologue for t=0) -> no stall.
        asm volatile("s_waitcnt vmcnt(0)" ::: "memory");
        __builtin_amdgcn_s_barrier();
        SCHED;

        if (t < 7) STAGE(t + 1, (t + 1) & 1);   // compile-time buf index
        SCHED;

        const int buf = t & 1;                  // compile-time after unroll
        const char* xbuf = (const char*)xs[buf];
        const char* vbuf = (const char*)vs[buf];
        const char* ubuf = (const char*)us[buf];

        bf16x8 a0 = *(const bf16x8*)(xbuf + aoff0);
        bf16x8 a1 = *(const bf16x8*)(xbuf + aoff1);
        __builtin_amdgcn_s_setprio(1);
#pragma unroll
        for (int cf = 0; cf < 8; ++cf) {
            bf16x8 bv = *(const bf16x8*)(vbuf + boff[cf]);
            bf16x8 bu = *(const bf16x8*)(ubuf + boff[cf]);
            accV[0][cf] = __builtin_amdgcn_mfma_f32_16x16x32_bf16(a0, bv, accV[0][cf], 0, 0, 0);
            accV[1][cf] = __builtin_amdgcn_mfma_f32_16x16x32_bf16(a1, bv, accV[1][cf], 0, 0, 0);
            accU[0][cf] = __builtin_amdgcn_mfma_f32_16x16x32_bf16(a0, bu, accU[0][cf], 0, 0, 0);
            accU[1][cf] = __builtin_amdgcn_mfma_f32_16x16x32_bf16(a1, bu, accU[1][cf], 0, 0, 0);
        }
        __builtin_amdgcn_s_setprio(0);
    }
#undef STAGE
#undef SCHED

    // ---- epilogue: gated = tanh(V)*sigmoid(U), dot w over l, 16-lane reduce ----
    const float* wrow = w + h * L_;
#pragma unroll
    for (int rf = 0; rf < 2; ++rf) {
        float plog[4] = {0.f, 0.f, 0.f, 0.f};
#pragma unroll
        for (int cf = 0; cf < 8; ++cf) {
            float wvv = wrow[cf * 16 + c];
#pragma unroll
            for (int i = 0; i < 4; ++i) {
                float vv = accV[rf][cf][i];
                float uu = accU[rf][cf][i];
                vv = fminf(fmaxf(vv, -20.f), 20.f);
                float A = __expf(2.f * vv);                 // tanh = (A-1)/(A+1)
                float E = __expf(fminf(-uu, 30.f));         // sigmoid = 1/(1+E)
                float gg = __fdividef(A - 1.f, (A + 1.f) * (1.f + E));
                plog[i] += gg * wvv;
            }
        }
#pragma unroll
        for (int i = 0; i < 4; ++i) {
            float v = plog[i];
            v += __shfl_xor(v, 1);
            v += __shfl_xor(v, 2);
            v += __shfl_xor(v, 4);
            v += __shfl_xor(v, 8);      // sum over the 16 col-lanes
            if (c == 0) {
                int rowflat = tile * 128 + wv * 32 + rf * 16 + g * 4 + i;
                int b = rowflat >> 12;           // / N_
                int n = rowflat & (N_ - 1);
                logits[((size_t)b * H_ + h) * N_ + n] = v;
            }
        }
    }
}

// ---------------------------------------------------------------------------
// SLOW PATH (round-1 fallback, used only if ws_size is too small)
// ---------------------------------------------------------------------------
__global__ void prep_vu_slow(const float* __restrict__ V, const float* __restrict__ U,
                             unsigned short* __restrict__ Vt, unsigned short* __restrict__ Ut) {
    int idx = blockIdx.x * 256 + threadIdx.x;
    int m = idx & (M_ - 1);
    int l = (idx >> 8) & (L_ - 1);
    int h = idx >> 15;
    Vt[idx] = f2bf(V[((size_t)h * M_ + m) * L_ + l]);
    Ut[idx] = f2bf(U[((size_t)h * M_ + m) * L_ + l]);
}

#define BM 128
#define BK 64

__global__ __launch_bounds__(256, 2)
void gemm_logits(const float* __restrict__ x,
                 const unsigned short* __restrict__ Vt,
                 const unsigned short* __restrict__ Ut,
                 const float* __restrict__ w,
                 float* __restrict__ logits) {
    __shared__ __align__(16) unsigned short xs[BM * BK];
    __shared__ __align__(16) unsigned short vs[L_ * BK];
    __shared__ __align__(16) unsigned short us[L_ * BK];
    __shared__ float wl[L_];

    const int h    = blockIdx.x >> 10;
    const int tile = blockIdx.x & 1023;
    const int row0 = tile * BM;
    const int tid  = threadIdx.x;
    const int lane = tid & 63;
    const int wave = tid >> 6;

    if (tid < L_) wl[tid] = w[h * L_ + tid];

    f32x4 accV[2][8], accU[2][8];
#pragma unroll
    for (int rf = 0; rf < 2; ++rf)
#pragma unroll
        for (int cf = 0; cf < 8; ++cf) {
            accV[rf][cf] = (f32x4){0.f, 0.f, 0.f, 0.f};
            accU[rf][cf] = (f32x4){0.f, 0.f, 0.f, 0.f};
        }

    const unsigned short* Vh = Vt + (size_t)h * L_ * M_;
    const unsigned short* Uh = Ut + (size_t)h * L_ * M_;
    const int g = lane >> 4;
    const int c = lane & 15;

    for (int ks = 0; ks < 4; ++ks) {
        const int k0 = ks * BK;
        __syncthreads();
#pragma unroll
        for (int p = 0; p < 4; ++p) {
            int row = p * 32 + (tid >> 3);
            int kk  = (tid & 7) * 8;
            const float* gx = x + (size_t)(row0 + row) * M_ + k0 + kk;
            float4 a = *(const float4*)gx;
            float4 b = *(const float4*)(gx + 4);
            uint4 o;
            o.x = pack2(a.x, a.y); o.y = pack2(a.z, a.w);
            o.z = pack2(b.x, b.y); o.w = pack2(b.z, b.w);
            int byte = (row * BK + kk) * 2;
            byte ^= (row & 7) << 4;
            *(uint4*)((char*)xs + byte) = o;
        }
#pragma unroll
        for (int p = 0; p < 4; ++p) {
            int l  = p * 32 + (tid >> 3);
            int kk = (tid & 7) * 8;
            uint4 v = *(const uint4*)(Vh + (size_t)l * M_ + k0 + kk);
            uint4 u = *(const uint4*)(Uh + (size_t)l * M_ + k0 + kk);
            int byte = (l * BK + kk) * 2;
            byte ^= (l & 7) << 4;
            *(uint4*)((char*)vs + byte) = v;
            *(uint4*)((char*)us + byte) = u;
        }
        __syncthreads();
#pragma unroll
        for (int ksub = 0; ksub < 2; ++ksub) {
            bf16x8 afr[2];
#pragma unroll
            for (int rf = 0; rf < 2; ++rf) {
                int row = wave * 32 + rf * 16 + c;
                int byte = (row * BK + ksub * 32 + g * 8) * 2;
                byte ^= (row & 7) << 4;
                afr[rf] = *(const bf16x8*)((const char*)xs + byte);
            }
#pragma unroll
            for (int cf = 0; cf < 8; ++cf) {
                int l = cf * 16 + c;
                int byte = (l * BK + ksub * 32 + g * 8) * 2;
                byte ^= (l & 7) << 4;
                bf16x8 bv = *(const bf16x8*)((const char*)vs + byte);
                bf16x8 bu = *(const bf16x8*)((const char*)us + byte);
#pragma unroll
                for (int rf = 0; rf < 2; ++rf) {
                    accV[rf][cf] = __builtin_amdgcn_mfma_f32_16x16x32_bf16(afr[rf], bv, accV[rf][cf], 0, 0, 0);
                    accU[rf][cf] = __builtin_amdgcn_mfma_f32_16x16x32_bf16(afr[rf], bu, accU[rf][cf], 0, 0, 0);
                }
            }
        }
    }
#pragma unroll
    for (int rf = 0; rf < 2; ++rf) {
        float plog[4] = {0.f, 0.f, 0.f, 0.f};
#pragma unroll
        for (int cf = 0; cf < 8; ++cf) {
            float wvv = wl[cf * 16 + c];
#pragma unroll
            for (int i = 0; i < 4; ++i) {
                float vv = accV[rf][cf][i];
                float uu = accU[rf][cf][i];
                vv = fminf(fmaxf(vv, -20.f), 20.f);
                float e2v = __expf(2.f * vv);
                float t = __fdividef(e2v - 1.f, e2v + 1.f);
                float s = __fdividef(1.f, 1.f + __expf(-uu));
                plog[i] += t * s * wvv;
            }
        }
#pragma unroll
        for (int i = 0; i < 4; ++i) {
            float v = plog[i];
            v += __shfl_xor(v, 1);
            v += __shfl_xor(v, 2);
            v += __shfl_xor(v, 4);
            v += __shfl_xor(v, 8);
            if (c == 0) {
                int rowflat = row0 + wave * 32 + rf * 16 + g * 4 + i;
                int b = rowflat >> 12;
                int n = rowflat & (N_ - 1);
                logits[((size_t)b * H_ + h) * N_ + n] = v;
            }
        }
    }
}

// ---------------------------------------------------------------------------
// softmax^2 (first normalization cancels): a = e^2/sum(e^2), e = m*exp(m*l).
// ---------------------------------------------------------------------------
__global__ __launch_bounds__(256)
void softmax_att(const float* __restrict__ logits, const float* __restrict__ masks,
                 float* __restrict__ att) {
    const int bh = blockIdx.x;
    const int b = bh >> 2, h = bh & 3;
    __shared__ float e2s[N_];
    __shared__ float red[4];
    const int tid = threadIdx.x;

    float sum = 0.f;
#pragma unroll
    for (int i = 0; i < N_ / 256; ++i) {
        int n = i * 256 + tid;
        float lg = logits[((size_t)b * H_ + h) * N_ + n];
        float mv = masks[(size_t)b * N_ + n];
        float e = mv * __expf(mv * lg);
        float e2 = e * e;
        e2s[n] = e2;
        sum += e2;
    }
#pragma unroll
    for (int off = 32; off >= 1; off >>= 1) sum += __shfl_xor(sum, off);
    if ((tid & 63) == 0) red[tid >> 6] = sum;
    __syncthreads();
    float S = red[0] + red[1] + red[2] + red[3];
    float inv = 1.f / S;
#pragma unroll
    for (int i = 0; i < N_ / 256; ++i) {
        int n = i * 256 + tid;
        att[((size_t)h * B_ + b) * N_ + n] = e2s[n] * inv;
    }
}

// ---------------------------------------------------------------------------
// emb: 2-stage deterministic reduction.
// ---------------------------------------------------------------------------
#define NCH 32
#define CHUNK (N_ / NCH)   // 128

__global__ __launch_bounds__(256)
void emb_partial(const float* __restrict__ x, const float* __restrict__ att,
                 float* __restrict__ part) {
    const int bc = blockIdx.x;
    const int b = bc >> 5, ch = bc & 31;
    __shared__ float as[H_][CHUNK];
    const int tid = threadIdx.x;

    for (int i = tid; i < H_ * CHUNK; i += 256) {
        int hh = i >> 7;
        int j  = i & (CHUNK - 1);
        as[hh][j] = att[((size_t)hh * B_ + b) * N_ + ch * CHUNK + j];
    }
    __syncthreads();

    float a0 = 0.f, a1 = 0.f, a2 = 0.f, a3 = 0.f;
    const float* xp = x + ((size_t)b * N_ + ch * CHUNK) * M_ + tid;
#pragma unroll 4
    for (int j = 0; j < CHUNK; ++j) {
        float xv = xp[(size_t)j * M_];
        a0 += as[0][j] * xv;
        a1 += as[1][j] * xv;
        a2 += as[2][j] * xv;
        a3 += as[3][j] * xv;
    }
    float* pp = part + (size_t)bc * H_ * M_ + tid;
    pp[0 * M_] = a0; pp[1 * M_] = a1; pp[2 * M_] = a2; pp[3 * M_] = a3;
}

__global__ __launch_bounds__(256)
void emb_reduce(const float* __restrict__ part, float* __restrict__ emb) {
    int idx = blockIdx.x * 256 + threadIdx.x;
    int b = idx >> 10;
    int r = idx & 1023;
    float s = 0.f;
#pragma unroll
    for (int ci = 0; ci < NCH; ++ci)
        s += part[((size_t)(b * NCH + ci)) * (H_ * M_) + r];
    emb[idx] = s;
}

// ---------------------------------------------------------------------------
extern "C" void kernel_launch(void* const* d_in, const int* in_sizes, int n_in,
                              void* d_out, int out_size, void* d_ws, size_t ws_size,
                              hipStream_t stream) {
    const float* x     = (const float*)d_in[0];
    const float* masks = (const float*)d_in[1];
    const float* V     = (const float*)d_in[2];
    const float* U     = (const float*)d_in[3];
    const float* w     = (const float*)d_in[4];

    float* att = (float*)d_out;                       // (H,B,N,1)
    float* emb = att + (size_t)H_ * B_ * N_;          // (B,H*M)

    char* ws = (char*)d_ws;
    const size_t XB_BYTES  = (size_t)1024 * 8 * 8192;         // 67,108,864
    const size_t VU_BYTES  = (size_t)64 * 8192;               // 524,288
    const size_t LG_BYTES  = (size_t)B_ * H_ * N_ * 4;        // 2,097,152
    const size_t PT_BYTES  = (size_t)B_ * NCH * H_ * M_ * 4;  // 4,194,304
    const size_t NEED_FAST = XB_BYTES + VU_BYTES + LG_BYTES + PT_BYTES;

    float* logits;
    float* partp;

    if (ws_size >= NEED_FAST) {
        unsigned short* xb = (unsigned short*)ws;
        unsigned short* vuimg = (unsigned short*)(ws + XB_BYTES);
        logits = (float*)(ws + XB_BYTES + VU_BYTES);
        partp  = (float*)(ws + XB_BYTES + VU_BYTES + LG_BYTES);

        prep_x     <<<4096, 256, 0, stream>>>(x, xb);
        prep_vu_img<<<32,   256, 0, stream>>>(V, U, vuimg);
        gemm_fast5 <<<4096, 256, 0, stream>>>(xb, vuimg, w, logits);
    } else {
        unsigned short* Vt = (unsigned short*)ws;
        unsigned short* Ut = (unsigned short*)(ws + 262144);
        logits = (float*)(ws + 524288);
        partp  = (float*)(ws + 524288 + LG_BYTES);

        prep_vu_slow<<<512, 256, 0, stream>>>(V, U, Vt, Ut);
        gemm_logits <<<4096, 256, 0, stream>>>(x, Vt, Ut, w, logits);
    }

    softmax_att<<<B_ * H_,              256, 0, stream>>>(logits, masks, att);
    emb_partial<<<B_ * NCH,             256, 0, stream>>>(x, att, partp);
    emb_reduce <<<(B_ * H_ * M_) / 256, 256, 0, stream>>>(partp, emb);
}

// Round 8
// 174.048 us; speedup vs baseline: 1.3271x; 1.0408x over previous
//
#include <hip/hip_runtime.h>
#include <hip/hip_bf16.h>
#include <stdint.h>

// Problem constants
#define B_ 32
#define N_ 4096
#define M_ 256
#define L_ 128
#define H_ 4
#define BN_ (B_ * N_)          // 131072 flattened rows

typedef __bf16 bf16x8 __attribute__((ext_vector_type(8)));
typedef float  f32x4  __attribute__((ext_vector_type(4)));

__device__ __forceinline__ unsigned short f2bf(float f) {
    // round-to-nearest-even f32 -> bf16
    unsigned int u = __float_as_uint(f);
    u += 0x7fffu + ((u >> 16) & 1u);
    return (unsigned short)(u >> 16);
}
__device__ __forceinline__ unsigned int pack2(float lo, float hi) {
    return (unsigned int)f2bf(lo) | ((unsigned int)f2bf(hi) << 16);
}

// async global->LDS, 16B per lane. LDS dest is wave-uniform base (+lane*16 by HW);
// global src is per-lane.
__device__ __forceinline__ void gload16(const void* g, void* l) {
    __builtin_amdgcn_global_load_lds(
        (const __attribute__((address_space(1))) unsigned int*)g,
        (__attribute__((address_space(3))) unsigned int*)l, 16, 0, 0);
}

// Image geometry: each K-step image is [128 rows][32 k] bf16 = 8192 B,
// row stride 64 B. Swizzle: byte ^= (row&14)<<3 — XORs byte bits 4..6 with
// row bits 1..3, giving 8 distinct 16B slots -> all 32 banks covered for the
// 16-lane fragment read pattern (the old (row&6)<<3 covered only banks 0-15).
// Bijective: XOR on fixed bit positions of the flat 8KB image address.

// ---------------------------------------------------------------------------
// prep 1: x (BN,256) f32 -> xb images: tile t in [0,1024), step s in [0,8):
// image base = (tile*8 + s)*8192.
// ---------------------------------------------------------------------------
__global__ void prep_x(const float* __restrict__ x, unsigned short* __restrict__ xb) {
    const int blk  = blockIdx.x;        // 4096 = 1024 tiles * 4 ks64
    const int tile = blk >> 2, ks = blk & 3;
    const int i    = threadIdx.x;
    const int kk   = (i & 7) * 8;       // 0..56 within the 64-col chunk
    const int tl   = kk >> 5;           // which 32-k image half
    const int kl   = kk & 31;
    char* dst = (char*)xb + ((size_t)tile * 8 + ks * 2 + tl) * 8192;
#pragma unroll
    for (int rep = 0; rep < 4; ++rep) {
        int row = rep * 32 + (i >> 3);
        const float* gx = x + (size_t)(tile * 128 + row) * M_ + ks * 64 + kk;
        float4 a = *(const float4*)gx;
        float4 b = *(const float4*)(gx + 4);
        uint4 o;
        o.x = pack2(a.x, a.y); o.y = pack2(a.z, a.w);
        o.z = pack2(b.x, b.y); o.w = pack2(b.z, b.w);
        int byte = (row * 64 + kl * 2) ^ ((row & 14) << 3);
        *(uint4*)(dst + byte) = o;
    }
}

// ---------------------------------------------------------------------------
// prep 2: V,U (H,M,L) f32 -> vu images [(h*8 + s)*2 + mat][128 l][32 m] bf16,
// swizzled. Transpose via padded LDS slab (conflict-free).
// ---------------------------------------------------------------------------
__global__ void prep_vu_img(const float* __restrict__ V, const float* __restrict__ U,
                            unsigned short* __restrict__ vu) {
    __shared__ float slab[64][129];     // [m][l], padded
    const int b   = blockIdx.x;         // 32 = h(4) * ks64(4) * mat(2)
    const int mat = b & 1, ks = (b >> 1) & 3, h = b >> 3;
    const float* src = (mat ? U : V) + ((size_t)h * M_ + ks * 64) * L_;
    const int tid = threadIdx.x;
#pragma unroll
    for (int rep = 0; rep < 32; ++rep) {
        int idx = rep * 256 + tid;      // 8192 = 64m x 128l
        slab[idx >> 7][idx & 127] = src[(size_t)(idx >> 7) * L_ + (idx & 127)];
    }
    __syncthreads();
#pragma unroll
    for (int rep = 0; rep < 4; ++rep) {
        int cidx = rep * 256 + tid;     // 1024 chunks of 16B (two 8KB images)
        int l  = cidx >> 3;             // 0..127
        int kk = (cidx & 7) * 8;        // 0..56
        uint4 o;
        o.x = pack2(slab[kk + 0][l], slab[kk + 1][l]);
        o.y = pack2(slab[kk + 2][l], slab[kk + 3][l]);
        o.z = pack2(slab[kk + 4][l], slab[kk + 5][l]);
        o.w = pack2(slab[kk + 6][l], slab[kk + 7][l]);
        int tl = kk >> 5, kl = kk & 31;
        char* dst = (char*)vu + (((size_t)(h * 8 + ks * 2 + tl)) * 2 + mat) * 8192;
        int byte = (l * 64 + kl * 2) ^ ((l & 14) << 3);
        *(uint4*)(dst + byte) = o;
    }
}

// ---------------------------------------------------------------------------
// gemm_fast6: 64x64 wave tiles (2x2 wave grid) + full-bank swizzle.
// logits[b,h,n] = sum_l tanh(xV)*sigmoid(xU)*w[h,l]
// 16x16x32 MFMA; block = 128 rows x 128 l x {V,U}, one (tile,h); 4 waves as
// (wr,wc) = (wv&1, wv>>1): wave tile = 64 rows x 64 l x {V,U}.
// Per wave-step: 4 A-reads + 8 B-reads (V4+U4) = 12 ds_read_b128 (was 18),
// 32 MFMA. A-frags reused 4x, B-frags 4x.
// BK=32, 8 unrolled steps, 2-buffer LDS (48KB -> 3 blocks/CU), 1-deep
// prefetch, vmcnt(0)+barrier per step, T5 setprio around MFMA cluster.
// ---------------------------------------------------------------------------
__global__ __launch_bounds__(256, 3)
void gemm_fast6(const unsigned short* __restrict__ xb,
                const unsigned short* __restrict__ vu,
                const float* __restrict__ w,
                float* __restrict__ logits) {
    __shared__ __align__(16) unsigned short xs[2][4096];   // 2 x 8KB
    __shared__ __align__(16) unsigned short vs[2][4096];
    __shared__ __align__(16) unsigned short us[2][4096];
    __shared__ float part[2][128];

    const int orig    = blockIdx.x;                 // 4096, %8==0 -> bijective
    const int logical = (orig & 7) * 512 + (orig >> 3);
    const int tile    = logical >> 2;
    const int h       = logical & 3;

    const int tid  = threadIdx.x;
    const int lane = tid & 63;
    const int wv   = tid >> 6;
    const int g    = lane >> 4;     // k-group 0..3 (k = g*8 + j)
    const int c    = lane & 15;     // row (A) / col (B) within fragment
    const int wr   = wv & 1;        // wave row half
    const int wc   = wv >> 1;       // wave l half

    f32x4 accV[4][4], accU[4][4];
#pragma unroll
    for (int rf = 0; rf < 4; ++rf)
#pragma unroll
        for (int cf = 0; cf < 4; ++cf) {
            accV[rf][cf] = (f32x4){0.f, 0.f, 0.f, 0.f};
            accU[rf][cf] = (f32x4){0.f, 0.f, 0.f, 0.f};
        }

    const int soff = wv * 2048;     // this wave's quarter of each 8KB image

    // hoisted per-lane global sources (step strides: x 8192 B, v/u 16384 B)
    const char* gxs = (const char*)xb + (size_t)tile * 65536 + soff + lane * 16;
    const char* gvs = (const char*)vu + (size_t)h * 131072 + soff + lane * 16;
    const char* gus = gvs + 8192;

    // hoisted swizzled LDS read byte offsets (within an 8KB image)
    int aoff[4], boff[4];
#pragma unroll
    for (int rf = 0; rf < 4; ++rf) {
        int r = wr * 64 + rf * 16 + c;
        aoff[rf] = (r * 64 + g * 16) ^ ((r & 14) << 3);
    }
#pragma unroll
    for (int cf = 0; cf < 4; ++cf) {
        int l = wc * 64 + cf * 16 + c;
        boff[cf] = (l * 64 + g * 16) ^ ((l & 14) << 3);
    }

#define SCHED __builtin_amdgcn_sched_barrier(0)

#define STAGE(t, bufi) do {                                          \
        const char* _gx = gxs + (t) * 8192;                          \
        const char* _gv = gvs + (t) * 16384;                         \
        const char* _gu = gus + (t) * 16384;                         \
        gload16(_gx,        (char*)xs[bufi] + soff);                 \
        gload16(_gx + 1024, (char*)xs[bufi] + soff + 1024);          \
        gload16(_gv,        (char*)vs[bufi] + soff);                 \
        gload16(_gv + 1024, (char*)vs[bufi] + soff + 1024);          \
        gload16(_gu,        (char*)us[bufi] + soff);                 \
        gload16(_gu + 1024, (char*)us[bufi] + soff + 1024);          \
    } while (0)

    // prologue: stage step 0 into buf 0
    STAGE(0, 0);
    SCHED;

#pragma unroll
    for (int t = 0; t < 8; ++t) {
        // stage(t) was issued a full step ago (prologue for t=0) -> no stall.
        asm volatile("s_waitcnt vmcnt(0)" ::: "memory");
        __builtin_amdgcn_s_barrier();
        SCHED;

        if (t < 7) STAGE(t + 1, (t + 1) & 1);   // compile-time buf index
        SCHED;

        const int buf = t & 1;                  // compile-time after unroll
        const char* xbuf = (const char*)xs[buf];
        const char* vbuf = (const char*)vs[buf];
        const char* ubuf = (const char*)us[buf];

        bf16x8 a0 = *(const bf16x8*)(xbuf + aoff[0]);
        bf16x8 a1 = *(const bf16x8*)(xbuf + aoff[1]);
        bf16x8 a2 = *(const bf16x8*)(xbuf + aoff[2]);
        bf16x8 a3 = *(const bf16x8*)(xbuf + aoff[3]);
        __builtin_amdgcn_s_setprio(1);
#pragma unroll
        for (int cf = 0; cf < 4; ++cf) {
            bf16x8 bv = *(const bf16x8*)(vbuf + boff[cf]);
            bf16x8 bu = *(const bf16x8*)(ubuf + boff[cf]);
            accV[0][cf] = __builtin_amdgcn_mfma_f32_16x16x32_bf16(a0, bv, accV[0][cf], 0, 0, 0);
            accV[1][cf] = __builtin_amdgcn_mfma_f32_16x16x32_bf16(a1, bv, accV[1][cf], 0, 0, 0);
            accV[2][cf] = __builtin_amdgcn_mfma_f32_16x16x32_bf16(a2, bv, accV[2][cf], 0, 0, 0);
            accV[3][cf] = __builtin_amdgcn_mfma_f32_16x16x32_bf16(a3, bv, accV[3][cf], 0, 0, 0);
            accU[0][cf] = __builtin_amdgcn_mfma_f32_16x16x32_bf16(a0, bu, accU[0][cf], 0, 0, 0);
            accU[1][cf] = __builtin_amdgcn_mfma_f32_16x16x32_bf16(a1, bu, accU[1][cf], 0, 0, 0);
            accU[2][cf] = __builtin_amdgcn_mfma_f32_16x16x32_bf16(a2, bu, accU[2][cf], 0, 0, 0);
            accU[3][cf] = __builtin_amdgcn_mfma_f32_16x16x32_bf16(a3, bu, accU[3][cf], 0, 0, 0);
        }
        __builtin_amdgcn_s_setprio(0);
    }
#undef STAGE
#undef SCHED

    // ---- epilogue: gated = tanh(V)*sigmoid(U), dot w over this wave's 64 l,
    //      16-lane shuffle reduce, join the two l-halves via LDS part[].
    const float* wrow = w + h * L_ + wc * 64;
#pragma unroll
    for (int rf = 0; rf < 4; ++rf) {
        float plog[4] = {0.f, 0.f, 0.f, 0.f};
#pragma unroll
        for (int cf = 0; cf < 4; ++cf) {
            float wvv = wrow[cf * 16 + c];
#pragma unroll
            for (int i = 0; i < 4; ++i) {
                float vv = accV[rf][cf][i];
                float uu = accU[rf][cf][i];
                vv = fminf(fmaxf(vv, -20.f), 20.f);
                float A = __expf(2.f * vv);                 // tanh = (A-1)/(A+1)
                float E = __expf(fminf(-uu, 30.f));         // sigmoid = 1/(1+E)
                float gg = __fdividef(A - 1.f, (A + 1.f) * (1.f + E));
                plog[i] += gg * wvv;
            }
        }
#pragma unroll
        for (int i = 0; i < 4; ++i) {
            float v = plog[i];
            v += __shfl_xor(v, 1);
            v += __shfl_xor(v, 2);
            v += __shfl_xor(v, 4);
            v += __shfl_xor(v, 8);      // sum over the 16 col-lanes
            if (c == 0)
                part[wc][wr * 64 + rf * 16 + g * 4 + i] = v;
        }
    }
    __syncthreads();
    if (tid < 128) {
        float v = part[0][tid] + part[1][tid];
        int rowflat = tile * 128 + tid;
        int b = rowflat >> 12;           // / N_
        int n = rowflat & (N_ - 1);
        logits[((size_t)b * H_ + h) * N_ + n] = v;
    }
}

// ---------------------------------------------------------------------------
// SLOW PATH (round-1 fallback, used only if ws_size is too small)
// ---------------------------------------------------------------------------
__global__ void prep_vu_slow(const float* __restrict__ V, const float* __restrict__ U,
                             unsigned short* __restrict__ Vt, unsigned short* __restrict__ Ut) {
    int idx = blockIdx.x * 256 + threadIdx.x;
    int m = idx & (M_ - 1);
    int l = (idx >> 8) & (L_ - 1);
    int h = idx >> 15;
    Vt[idx] = f2bf(V[((size_t)h * M_ + m) * L_ + l]);
    Ut[idx] = f2bf(U[((size_t)h * M_ + m) * L_ + l]);
}

#define BM 128
#define BK 64

__global__ __launch_bounds__(256, 2)
void gemm_logits(const float* __restrict__ x,
                 const unsigned short* __restrict__ Vt,
                 const unsigned short* __restrict__ Ut,
                 const float* __restrict__ w,
                 float* __restrict__ logits) {
    __shared__ __align__(16) unsigned short xs[BM * BK];
    __shared__ __align__(16) unsigned short vs[L_ * BK];
    __shared__ __align__(16) unsigned short us[L_ * BK];
    __shared__ float wl[L_];

    const int h    = blockIdx.x >> 10;
    const int tile = blockIdx.x & 1023;
    const int row0 = tile * BM;
    const int tid  = threadIdx.x;
    const int lane = tid & 63;
    const int wave = tid >> 6;

    if (tid < L_) wl[tid] = w[h * L_ + tid];

    f32x4 accV[2][8], accU[2][8];
#pragma unroll
    for (int rf = 0; rf < 2; ++rf)
#pragma unroll
        for (int cf = 0; cf < 8; ++cf) {
            accV[rf][cf] = (f32x4){0.f, 0.f, 0.f, 0.f};
            accU[rf][cf] = (f32x4){0.f, 0.f, 0.f, 0.f};
        }

    const unsigned short* Vh = Vt + (size_t)h * L_ * M_;
    const unsigned short* Uh = Ut + (size_t)h * L_ * M_;
    const int g = lane >> 4;
    const int c = lane & 15;

    for (int ks = 0; ks < 4; ++ks) {
        const int k0 = ks * BK;
        __syncthreads();
#pragma unroll
        for (int p = 0; p < 4; ++p) {
            int row = p * 32 + (tid >> 3);
            int kk  = (tid & 7) * 8;
            const float* gx = x + (size_t)(row0 + row) * M_ + k0 + kk;
            float4 a = *(const float4*)gx;
            float4 b = *(const float4*)(gx + 4);
            uint4 o;
            o.x = pack2(a.x, a.y); o.y = pack2(a.z, a.w);
            o.z = pack2(b.x, b.y); o.w = pack2(b.z, b.w);
            int byte = (row * BK + kk) * 2;
            byte ^= (row & 7) << 4;
            *(uint4*)((char*)xs + byte) = o;
        }
#pragma unroll
        for (int p = 0; p < 4; ++p) {
            int l  = p * 32 + (tid >> 3);
            int kk = (tid & 7) * 8;
            uint4 v = *(const uint4*)(Vh + (size_t)l * M_ + k0 + kk);
            uint4 u = *(const uint4*)(Uh + (size_t)l * M_ + k0 + kk);
            int byte = (l * BK + kk) * 2;
            byte ^= (l & 7) << 4;
            *(uint4*)((char*)vs + byte) = v;
            *(uint4*)((char*)us + byte) = u;
        }
        __syncthreads();
#pragma unroll
        for (int ksub = 0; ksub < 2; ++ksub) {
            bf16x8 afr[2];
#pragma unroll
            for (int rf = 0; rf < 2; ++rf) {
                int row = wave * 32 + rf * 16 + c;
                int byte = (row * BK + ksub * 32 + g * 8) * 2;
                byte ^= (row & 7) << 4;
                afr[rf] = *(const bf16x8*)((const char*)xs + byte);
            }
#pragma unroll
            for (int cf = 0; cf < 8; ++cf) {
                int l = cf * 16 + c;
                int byte = (l * BK + ksub * 32 + g * 8) * 2;
                byte ^= (l & 7) << 4;
                bf16x8 bv = *(const bf16x8*)((const char*)vs + byte);
                bf16x8 bu = *(const bf16x8*)((const char*)us + byte);
#pragma unroll
                for (int rf = 0; rf < 2; ++rf) {
                    accV[rf][cf] = __builtin_amdgcn_mfma_f32_16x16x32_bf16(afr[rf], bv, accV[rf][cf], 0, 0, 0);
                    accU[rf][cf] = __builtin_amdgcn_mfma_f32_16x16x32_bf16(afr[rf], bu, accU[rf][cf], 0, 0, 0);
                }
            }
        }
    }
#pragma unroll
    for (int rf = 0; rf < 2; ++rf) {
        float plog[4] = {0.f, 0.f, 0.f, 0.f};
#pragma unroll
        for (int cf = 0; cf < 8; ++cf) {
            float wvv = wl[cf * 16 + c];
#pragma unroll
            for (int i = 0; i < 4; ++i) {
                float vv = accV[rf][cf][i];
                float uu = accU[rf][cf][i];
                vv = fminf(fmaxf(vv, -20.f), 20.f);
                float e2v = __expf(2.f * vv);
                float t = __fdividef(e2v - 1.f, e2v + 1.f);
                float s = __fdividef(1.f, 1.f + __expf(-uu));
                plog[i] += t * s * wvv;
            }
        }
#pragma unroll
        for (int i = 0; i < 4; ++i) {
            float v = plog[i];
            v += __shfl_xor(v, 1);
            v += __shfl_xor(v, 2);
            v += __shfl_xor(v, 4);
            v += __shfl_xor(v, 8);
            if (c == 0) {
                int rowflat = row0 + wave * 32 + rf * 16 + g * 4 + i;
                int b = rowflat >> 12;
                int n = rowflat & (N_ - 1);
                logits[((size_t)b * H_ + h) * N_ + n] = v;
            }
        }
    }
}

// ---------------------------------------------------------------------------
// softmax^2 (first normalization cancels): a = e^2/sum(e^2), e = m*exp(m*l).
// ---------------------------------------------------------------------------
__global__ __launch_bounds__(256)
void softmax_att(const float* __restrict__ logits, const float* __restrict__ masks,
                 float* __restrict__ att) {
    const int bh = blockIdx.x;
    const int b = bh >> 2, h = bh & 3;
    __shared__ float e2s[N_];
    __shared__ float red[4];
    const int tid = threadIdx.x;

    float sum = 0.f;
#pragma unroll
    for (int i = 0; i < N_ / 256; ++i) {
        int n = i * 256 + tid;
        float lg = logits[((size_t)b * H_ + h) * N_ + n];
        float mv = masks[(size_t)b * N_ + n];
        float e = mv * __expf(mv * lg);
        float e2 = e * e;
        e2s[n] = e2;
        sum += e2;
    }
#pragma unroll
    for (int off = 32; off >= 1; off >>= 1) sum += __shfl_xor(sum, off);
    if ((tid & 63) == 0) red[tid >> 6] = sum;
    __syncthreads();
    float S = red[0] + red[1] + red[2] + red[3];
    float inv = 1.f / S;
#pragma unroll
    for (int i = 0; i < N_ / 256; ++i) {
        int n = i * 256 + tid;
        att[((size_t)h * B_ + b) * N_ + n] = e2s[n] * inv;
    }
}

// ---------------------------------------------------------------------------
// emb: 2-stage deterministic reduction.
// ---------------------------------------------------------------------------
#define NCH 32
#define CHUNK (N_ / NCH)   // 128

__global__ __launch_bounds__(256)
void emb_partial(const float* __restrict__ x, const float* __restrict__ att,
                 float* __restrict__ part) {
    const int bc = blockIdx.x;
    const int b = bc >> 5, ch = bc & 31;
    __shared__ float as[H_][CHUNK];
    const int tid = threadIdx.x;

    for (int i = tid; i < H_ * CHUNK; i += 256) {
        int hh = i >> 7;
        int j  = i & (CHUNK - 1);
        as[hh][j] = att[((size_t)hh * B_ + b) * N_ + ch * CHUNK + j];
    }
    __syncthreads();

    float a0 = 0.f, a1 = 0.f, a2 = 0.f, a3 = 0.f;
    const float* xp = x + ((size_t)b * N_ + ch * CHUNK) * M_ + tid;
#pragma unroll 4
    for (int j = 0; j < CHUNK; ++j) {
        float xv = xp[(size_t)j * M_];
        a0 += as[0][j] * xv;
        a1 += as[1][j] * xv;
        a2 += as[2][j] * xv;
        a3 += as[3][j] * xv;
    }
    float* pp = part + (size_t)bc * H_ * M_ + tid;
    pp[0 * M_] = a0; pp[1 * M_] = a1; pp[2 * M_] = a2; pp[3 * M_] = a3;
}

__global__ __launch_bounds__(256)
void emb_reduce(const float* __restrict__ part, float* __restrict__ emb) {
    int idx = blockIdx.x * 256 + threadIdx.x;
    int b = idx >> 10;
    int r = idx & 1023;
    float s = 0.f;
#pragma unroll
    for (int ci = 0; ci < NCH; ++ci)
        s += part[((size_t)(b * NCH + ci)) * (H_ * M_) + r];
    emb[idx] = s;
}

// ---------------------------------------------------------------------------
extern "C" void kernel_launch(void* const* d_in, const int* in_sizes, int n_in,
                              void* d_out, int out_size, void* d_ws, size_t ws_size,
                              hipStream_t stream) {
    const float* x     = (const float*)d_in[0];
    const float* masks = (const float*)d_in[1];
    const float* V     = (const float*)d_in[2];
    const float* U     = (const float*)d_in[3];
    const float* w     = (const float*)d_in[4];

    float* att = (float*)d_out;                       // (H,B,N,1)
    float* emb = att + (size_t)H_ * B_ * N_;          // (B,H*M)

    char* ws = (char*)d_ws;
    const size_t XB_BYTES  = (size_t)1024 * 8 * 8192;         // 67,108,864
    const size_t VU_BYTES  = (size_t)64 * 8192;               // 524,288
    const size_t LG_BYTES  = (size_t)B_ * H_ * N_ * 4;        // 2,097,152
    const size_t PT_BYTES  = (size_t)B_ * NCH * H_ * M_ * 4;  // 4,194,304
    const size_t NEED_FAST = XB_BYTES + VU_BYTES + LG_BYTES + PT_BYTES;

    float* logits;
    float* partp;

    if (ws_size >= NEED_FAST) {
        unsigned short* xb = (unsigned short*)ws;
        unsigned short* vuimg = (unsigned short*)(ws + XB_BYTES);
        logits = (float*)(ws + XB_BYTES + VU_BYTES);
        partp  = (float*)(ws + XB_BYTES + VU_BYTES + LG_BYTES);

        prep_x     <<<4096, 256, 0, stream>>>(x, xb);
        prep_vu_img<<<32,   256, 0, stream>>>(V, U, vuimg);
        gemm_fast6 <<<4096, 256, 0, stream>>>(xb, vuimg, w, logits);
    } else {
        unsigned short* Vt = (unsigned short*)ws;
        unsigned short* Ut = (unsigned short*)(ws + 262144);
        logits = (float*)(ws + 524288);
        partp  = (float*)(ws + 524288 + LG_BYTES);

        prep_vu_slow<<<512, 256, 0, stream>>>(V, U, Vt, Ut);
        gemm_logits <<<4096, 256, 0, stream>>>(x, Vt, Ut, w, logits);
    }

    softmax_att<<<B_ * H_,              256, 0, stream>>>(logits, masks, att);
    emb_partial<<<B_ * NCH,             256, 0, stream>>>(x, att, partp);
    emb_reduce <<<(B_ * H_ * M_) / 256, 256, 0, stream>>>(partp, emb);
}